// Round 4
// baseline (201.905 us; speedup 1.0000x reference)
//
#include <hip/hip_runtime.h>

// Boundary_binaryLoss: 15x15 binary morphology boundary mask + masked NLL mean.
// B=32, C=2, H=480, W=864. logits [B,C,H,W] f32, labels [B,H,W] i32 in {0,1,255}.
//
// valid(b,h,w) = (label != 255) && (15x15 clipped window contains np0 AND np255)
//   np0: label in {0,255}; np255: label==1
// loss = -sum(valid ? logits[b,label,h,w] : 0) / max(#valid, 1)
//
// R1: same-line atomics serialized -> per-block partials (180->64us).
// R2/R3: prefetch neutral; VALUBusy 30%, HBM 25% -> latency/issue-bound fat
//   block (2 barriers, 30 LDS reads/thread V-OR, dual sraw/sflag staging).
// R4: (a) 3-bit flags, no sraw; (b) H-OR writes TRANSPOSED bytes (column-major,
//   52B stride) so V-OR is SWAR over 6 dword reads/thread instead of 15x reads;
//   center flag packed in bits 2-4 of the same bytes; (c) waves stage+H-OR
//   their own rows -> ONE barrier; per-wave global partials -> no 2nd barrier.

namespace {
constexpr int B_ = 32;
constexpr int H_ = 480;
constexpr int W_ = 864;
constexpr int TW = 64;
constexpr int TH = 32;
constexpr int R_ = 7;
constexpr int LH = TH + 2 * R_;   // 46 halo rows
constexpr int WC = 20;            // 80 halo bytes per row, as dwords
constexpr int CPW = 13;           // colbuf dwords per column (52 B >= 46 rows)
constexpr int GX = (W_ + TW - 1) / TW;  // 14
constexpr int GY = H_ / TH;             // 15
constexpr int NBLK = GX * GY * B_;      // 6720
constexpr int NPART = NBLK * 4;         // one partial per wave
} // namespace

__device__ __forceinline__ unsigned fold4(unsigned x) {
  x |= x >> 16;
  x |= x >> 8;
  return x & 0xFFu;
}

__device__ __forceinline__ unsigned flag3(int v) {
  // bit0: np_label==0 (v==0 or v==255), bit1: np_label==255 (v==1), bit2: v==255
  return (v == 0) ? 1u : ((v == 1) ? 2u : ((v == 255) ? 5u : 0u));
}

extern "C" __global__ __launch_bounds__(256, 6)
void boundary_loss_main(const float* __restrict__ logits,
                        const int* __restrict__ labels,
                        double2* __restrict__ partials)
{
  __shared__ unsigned sflag[LH][WC];    // 3680 B: per-byte 3-bit flags, row-major
  __shared__ unsigned colbuf[TW][CPW];  // 3328 B: transposed H-OR bytes, col-major
                                        // byte r of col c: bits0-1 = 15-wide H-OR,
                                        // bits2-4 = center flag of (r,c)

  const int tid = threadIdx.x;
  const int wv = tid >> 6;
  const int lane = tid & 63;
  const int tile_w = blockIdx.x * TW;
  const int tile_h = blockIdx.y * TH;
  const int b = blockIdx.z;

  const int* __restrict__ lab = labels + (size_t)b * H_ * W_;
  const float* __restrict__ lg0 = logits + (size_t)b * 2 * H_ * W_;
  const float* __restrict__ lg1 = lg0 + (size_t)H_ * W_;

  // ---- logits prefetch: thread -> (col c, row group q), coalesced per row ----
  const int c = tid & 63;
  const int q = tid >> 6;
  const int gw = tile_w + c;
  const bool inb = gw < W_;  // last tile covers only 32 real cols
  float L0[8], L1[8];
  if (inb) {
    const float* p0 = lg0 + (size_t)(tile_h + 8 * q) * W_ + gw;
    const float* p1 = lg1 + (size_t)(tile_h + 8 * q) * W_ + gw;
#pragma unroll
    for (int rr = 0; rr < 8; ++rr) { L0[rr] = p0[(size_t)rr * W_]; L1[rr] = p1[(size_t)rr * W_]; }
  } else {
#pragma unroll
    for (int rr = 0; rr < 8; ++rr) { L0[rr] = 0.f; L1[rr] = 0.f; }
  }

  // ---- phase 1: each wave stages its OWN halo rows (12,12,12,10) ----
  const int row0 = wv * 12;
  const int nrows = (LH - row0) < 12 ? (LH - row0) : 12;
  int4 lv[4];
#pragma unroll
  for (int u = 0; u < 4; ++u) {
    const int idx = u * 64 + lane;
    lv[u] = make_int4(200, 200, 200, 200);  // OOB: flag 0
    if (idx < nrows * WC) {
      const int r = row0 + idx / WC;
      const int wc = idx % WC;
      const int gh = tile_h - R_ + r;
      const int gwl = tile_w - 8 + wc * 4;  // 16B-aligned; fully in or fully out
      if (gh >= 0 && gh < H_ && gwl >= 0 && gwl < W_)
        lv[u] = *(const int4*)(lab + (size_t)gh * W_ + gwl);
    }
  }
#pragma unroll
  for (int u = 0; u < 4; ++u) {
    const int idx = u * 64 + lane;
    if (idx < nrows * WC) {
      const int r = row0 + idx / WC;
      const int wc = idx % WC;
      const int4 v = lv[u];
      sflag[r][wc] = flag3(v.x) | (flag3(v.y) << 8) | (flag3(v.z) << 16) |
                     (flag3(v.w) << 24);
    }
  }

  // ---- phase 2: horizontal 15-OR on own rows, write transposed bytes ----
  // (intra-wave LDS dependency only -> no barrier needed before this)
  unsigned char* cb = (unsigned char*)&colbuf[0][0];
#pragma unroll
  for (int u = 0; u < 3; ++u) {
    const int idx = u * 64 + lane;
    if (idx < nrows * 16) {
      const int r = row0 + (idx >> 4);
      const int wc = idx & 15;
      const unsigned w0 = sflag[r][wc];
      const unsigned w1 = sflag[r][wc + 1];
      const unsigned w2 = sflag[r][wc + 2];  // also the center-flag dword
      const unsigned w3 = sflag[r][wc + 3];
      const unsigned w4 = sflag[r][wc + 4];
      const unsigned core = fold4(w1 | w2 | w3);
      const unsigned o0 = core | fold4(w0 >> 8);
      const unsigned o1 = core | fold4(w0 >> 16) | (w4 & 0xFFu);
      const unsigned o2 = core | (w0 >> 24) | fold4(w4 & 0xFFFFu);
      const unsigned o3 = core | fold4(w4 & 0xFFFFFFu);
      const int cbase = 4 * wc;
      cb[(cbase + 0) * 52 + r] = (unsigned char)((o0 & 3u) | ((w2 & 7u) << 2));
      cb[(cbase + 1) * 52 + r] = (unsigned char)((o1 & 3u) | (((w2 >> 8) & 7u) << 2));
      cb[(cbase + 2) * 52 + r] = (unsigned char)((o2 & 3u) | (((w2 >> 16) & 7u) << 2));
      cb[(cbase + 3) * 52 + r] = (unsigned char)((o3 & 3u) | (((w2 >> 24) & 7u) << 2));
    }
  }
  __syncthreads();  // the ONLY barrier

  // ---- phase 3: vertical 15-OR via SWAR on 6 column dwords + NLL gather ----
  double lsum = 0.0;
  unsigned lcnt = 0;
  if (inb) {
    unsigned d[6];
#pragma unroll
    for (int k = 0; k < 6; ++k) d[k] = colbuf[c][2 * q + k];  // rows 8q..8q+23
#pragma unroll
    for (int m = 0; m < 2; ++m) {
      // out-dword rows 8q+4m .. +3; needs column bytes (8q+4m)..(8q+4m+17)
      const unsigned M = 0x03030303u;
      const unsigned A0 = d[m] & M, A1 = d[m + 1] & M, A2 = d[m + 2] & M,
                     A3 = d[m + 3] & M, A4 = d[m + 4] & M;
      const unsigned Cc = fold4(A1 | A2);
      const unsigned f3v = fold4(A3);
      const unsigned o0 = fold4(A0) | Cc | fold4(A3 & 0x00FFFFFFu);
      const unsigned o1 = fold4(A0 >> 8) | Cc | f3v;
      const unsigned o2 = fold4(A0 >> 16) | Cc | f3v | (A4 & 0xFFu);
      const unsigned o3 = (A0 >> 24) | Cc | f3v | fold4(A4 & 0xFFFFu);
      // center flag bytes: column bytes (8q+4m+7)..(+10) = d[m+1]b3, d[m+2]b0-2
      const unsigned cen = (d[m + 1] >> 24) | (d[m + 2] << 8);
      const unsigned ov[4] = {o0, o1, o2, o3};
#pragma unroll
      for (int j = 0; j < 4; ++j) {
        const unsigned cbj = (cen >> (8 * j)) & 0xFFu;
        const bool valid = (ov[j] == 3u) && ((cbj & 0x10u) == 0u);  // bit4=ignore
        const int rr = 4 * m + j;
        const float v = (cbj & 0x08u) ? L1[rr] : L0[rr];  // bit3 = label==1
        lsum += valid ? (double)v : 0.0;
        lcnt += valid;
      }
    }
  }

  // ---- per-wave reduction -> one double2 per WAVE (no 2nd barrier) ----
#pragma unroll
  for (int off = 32; off > 0; off >>= 1) {
    lsum += __shfl_down(lsum, off, 64);
    lcnt += __shfl_down(lcnt, off, 64);
  }
  if (lane == 0) {
    const int bid = (blockIdx.z * GY + blockIdx.y) * GX + blockIdx.x;
    partials[bid * 4 + wv] = make_double2(lsum, (double)lcnt);
  }
}

extern "C" __global__ __launch_bounds__(1024)
void boundary_loss_final(const double2* __restrict__ partials,
                         float* __restrict__ out)
{
  __shared__ double red_s[16];
  __shared__ double red_c[16];
  const int tid = threadIdx.x;
  double s = 0.0, cc = 0.0;
  for (int i = tid; i < NPART; i += 1024) {
    const double2 p = partials[i];
    s += p.x;
    cc += p.y;
  }
#pragma unroll
  for (int off = 32; off > 0; off >>= 1) {
    s += __shfl_down(s, off, 64);
    cc += __shfl_down(cc, off, 64);
  }
  const int wave = tid >> 6;
  if ((tid & 63) == 0) { red_s[wave] = s; red_c[wave] = cc; }
  __syncthreads();
  if (tid == 0) {
    double ts = 0.0, tc = 0.0;
#pragma unroll
    for (int i = 0; i < 16; ++i) { ts += red_s[i]; tc += red_c[i]; }
    if (tc < 1.0) tc = 1.0;
    out[0] = (float)(-ts / tc);
  }
}

extern "C" void kernel_launch(void* const* d_in, const int* in_sizes, int n_in,
                              void* d_out, int out_size, void* d_ws, size_t ws_size,
                              hipStream_t stream)
{
  const float* logits = (const float*)d_in[0];
  const int* labels = (const int*)d_in[1];
  float* out = (float*)d_out;
  double2* partials = (double2*)d_ws;  // NPART*16 B = 430,080 B; every slot
                                       // written by main -> no init needed.

  dim3 grid(GX, GY, B_);
  boundary_loss_main<<<grid, 256, 0, stream>>>(logits, labels, partials);
  boundary_loss_final<<<1, 1024, 0, stream>>>(partials, out);
}

// Round 5
// 200.229 us; speedup vs baseline: 1.0084x; 1.0084x over previous
//
#include <hip/hip_runtime.h>

// Boundary_binaryLoss: 15x15 binary morphology boundary mask + masked NLL mean.
// B=32, C=2, H=480, W=864. logits [B,C,H,W] f32, labels [B,H,W] i32 in {0,1,255}.
//
// valid(b,h,w) = (label != 255) && (15x15 clipped window contains np0 AND np255)
// loss = -sum(valid ? logits[b,label,h,w] : 0) / max(#valid, 1)
//
// R1: same-line atomics serialized -> per-block partials (180->64us).
// R2-R4: register prefetch of logits was NEUTRAL - VGPR_Count=24 proves the
//   compiler sank the loads back to their use (32+ regs of "prefetched" data
//   cannot live in 24 VGPRs). Both pipes idle (VALU 34%, HBM 24%).
// R5: logits staged via __builtin_amdgcn_global_load_lds (width=16): 4
//   issues/wave, no data VGPRs, cannot be sunk, drained by the one existing
//   barrier. Phase 3 reads slog[label][row][col] from LDS (8 conflict-free
//   ds_read_b32). Accumulation dropped to fp32+u32 (error budget ~105 abs on
//   the sum; fp32 worst case ~5e-3) halving the reduction chain.

namespace {
constexpr int B_ = 32;
constexpr int H_ = 480;
constexpr int W_ = 864;
constexpr int TW = 64;
constexpr int TH = 32;
constexpr int R_ = 7;
constexpr int LH = TH + 2 * R_;   // 46 halo rows
constexpr int WC = 20;            // 80 halo bytes per row, as dwords
constexpr int CPW = 13;           // colbuf dwords per column (52 B >= 46 rows)
constexpr int GX = (W_ + TW - 1) / TW;  // 14
constexpr int GY = H_ / TH;             // 15
constexpr int NBLK = GX * GY * B_;      // 6720
constexpr int NPART = NBLK * 4;         // one partial per wave
} // namespace

__device__ __forceinline__ unsigned fold4(unsigned x) {
  x |= x >> 16;
  x |= x >> 8;
  return x & 0xFFu;
}

__device__ __forceinline__ unsigned flag3(int v) {
  // bit0: np_label==0 (v==0 or v==255), bit1: np_label==255 (v==1), bit2: v==255
  return (v == 0) ? 1u : ((v == 1) ? 2u : ((v == 255) ? 5u : 0u));
}

// async global->LDS, 16 B per lane; LDS dest is wave-uniform base + lane*16
// (compiler readfirstlanes the pointer), so pass base + lane*16 per-lane.
__device__ __forceinline__ void glds16(void* lds, const void* g) {
  __builtin_amdgcn_global_load_lds(
      (const __attribute__((address_space(1))) void*)g,
      (__attribute__((address_space(3))) void*)lds, 16, 0, 0);
}

extern "C" __global__ __launch_bounds__(256, 6)
void boundary_loss_main(const float* __restrict__ logits,
                        const int* __restrict__ labels,
                        float2* __restrict__ partials)
{
  __shared__ float slog[2][TH][TW];     // 16384 B: logits tile, both channels
  __shared__ unsigned sflag[LH][WC];    // 3680 B: per-byte 3-bit flags
  __shared__ unsigned colbuf[TW][CPW];  // 3328 B: transposed H-OR bytes
                                        // byte r of col c: bits0-1 = H-OR,
                                        // bits2-4 = center flag of (r,c)

  const int tid = threadIdx.x;
  const int wv = tid >> 6;
  const int lane = tid & 63;
  const int tile_w = blockIdx.x * TW;
  const int tile_h = blockIdx.y * TH;
  const int b = blockIdx.z;

  const int* __restrict__ lab = labels + (size_t)b * H_ * W_;
  const float* __restrict__ lg = logits + (size_t)b * 2 * H_ * W_;

  // ---- issue async logits->LDS FIRST: 4 x global_load_lds_dwordx4 per wave.
  // issue i in [0,16): ch = i>>3, rowgroup rg = i&7 (4 rows); slog byte offset
  // of (ch, rg*4+lane/16, (lane%16)*4) == i*1024 + lane*16. Last tile: clamp
  // global col (duplicate reads, masked by `inb` in phase 3).
  {
    const int lrow = lane >> 4;                       // 0..3
    const int lcol = (lane & 15) * 4;                 // 0..60
    int gcol = tile_w + lcol;
    if (gcol > W_ - 4) gcol = W_ - 4;
    char* lbase = (char*)&slog[0][0][0] + lane * 16;
#pragma unroll
    for (int u = 0; u < 4; ++u) {
      const int i = wv * 4 + u;
      const int ch = i >> 3;
      const int rg = i & 7;
      const float* g = lg + (size_t)ch * H_ * W_ +
                       (size_t)(tile_h + rg * 4 + lrow) * W_ + gcol;
      glds16(lbase + i * 1024, g);
    }
  }

  // ---- phase 1: each wave stages its OWN halo rows (12,12,12,10) ----
  const int row0 = wv * 12;
  const int nrows = (LH - row0) < 12 ? (LH - row0) : 12;
  int4 lv[4];
#pragma unroll
  for (int u = 0; u < 4; ++u) {
    const int idx = u * 64 + lane;
    lv[u] = make_int4(200, 200, 200, 200);  // OOB: flag 0
    if (idx < nrows * WC) {
      const int r = row0 + idx / WC;
      const int wc = idx % WC;
      const int gh = tile_h - R_ + r;
      const int gwl = tile_w - 8 + wc * 4;  // 16B-aligned; fully in or fully out
      if (gh >= 0 && gh < H_ && gwl >= 0 && gwl < W_)
        lv[u] = *(const int4*)(lab + (size_t)gh * W_ + gwl);
    }
  }
#pragma unroll
  for (int u = 0; u < 4; ++u) {
    const int idx = u * 64 + lane;
    if (idx < nrows * WC) {
      const int r = row0 + idx / WC;
      const int wc = idx % WC;
      const int4 v = lv[u];
      sflag[r][wc] = flag3(v.x) | (flag3(v.y) << 8) | (flag3(v.z) << 16) |
                     (flag3(v.w) << 24);
    }
  }

  // ---- phase 2: horizontal 15-OR on own rows, write transposed bytes ----
  // (intra-wave LDS dependency only -> no barrier needed before this)
  unsigned char* cb = (unsigned char*)&colbuf[0][0];
#pragma unroll
  for (int u = 0; u < 3; ++u) {
    const int idx = u * 64 + lane;
    if (idx < nrows * 16) {
      const int r = row0 + (idx >> 4);
      const int wc = idx & 15;
      const unsigned w0 = sflag[r][wc];
      const unsigned w1 = sflag[r][wc + 1];
      const unsigned w2 = sflag[r][wc + 2];  // also the center-flag dword
      const unsigned w3 = sflag[r][wc + 3];
      const unsigned w4 = sflag[r][wc + 4];
      const unsigned core = fold4(w1 | w2 | w3);
      const unsigned o0 = core | fold4(w0 >> 8);
      const unsigned o1 = core | fold4(w0 >> 16) | (w4 & 0xFFu);
      const unsigned o2 = core | (w0 >> 24) | fold4(w4 & 0xFFFFu);
      const unsigned o3 = core | fold4(w4 & 0xFFFFFFu);
      const int cbase = 4 * wc;
      cb[(cbase + 0) * 52 + r] = (unsigned char)((o0 & 3u) | ((w2 & 7u) << 2));
      cb[(cbase + 1) * 52 + r] = (unsigned char)((o1 & 3u) | (((w2 >> 8) & 7u) << 2));
      cb[(cbase + 2) * 52 + r] = (unsigned char)((o2 & 3u) | (((w2 >> 16) & 7u) << 2));
      cb[(cbase + 3) * 52 + r] = (unsigned char)((o3 & 3u) | (((w2 >> 24) & 7u) << 2));
    }
  }
  __syncthreads();  // the ONLY barrier; also drains the async logits (vmcnt)

  // ---- phase 3: vertical 15-OR via SWAR on 6 column dwords + NLL gather ----
  float lsum = 0.f;
  unsigned lcnt = 0;
  const int c = lane;       // column within tile
  const int q = wv;         // row group (8 rows)
  const bool inb = (tile_w + c) < W_;
  if (inb) {
    unsigned d[6];
#pragma unroll
    for (int k = 0; k < 6; ++k) d[k] = colbuf[c][2 * q + k];  // rows 8q..8q+23
#pragma unroll
    for (int m = 0; m < 2; ++m) {
      const unsigned M = 0x03030303u;
      const unsigned A0 = d[m] & M, A1 = d[m + 1] & M, A2 = d[m + 2] & M,
                     A3 = d[m + 3] & M, A4 = d[m + 4] & M;
      const unsigned Cc = fold4(A1 | A2);
      const unsigned f3v = fold4(A3);
      const unsigned o0 = fold4(A0) | Cc | fold4(A3 & 0x00FFFFFFu);
      const unsigned o1 = fold4(A0 >> 8) | Cc | f3v;
      const unsigned o2 = fold4(A0 >> 16) | Cc | f3v | (A4 & 0xFFu);
      const unsigned o3 = (A0 >> 24) | Cc | f3v | fold4(A4 & 0xFFFFu);
      // center flag bytes: column bytes (8q+4m+7)..(+10)
      const unsigned cen = (d[m + 1] >> 24) | (d[m + 2] << 8);
      const unsigned ov[4] = {o0, o1, o2, o3};
#pragma unroll
      for (int j = 0; j < 4; ++j) {
        const unsigned cbj = (cen >> (8 * j)) & 0xFFu;
        const bool valid = (ov[j] == 3u) && ((cbj & 0x10u) == 0u);  // bit4=ignore
        const int row = 8 * q + 4 * m + j;
        const float v = slog[(cbj >> 3) & 1u][row][c];  // bit3 = label==1
        lsum += valid ? v : 0.f;
        lcnt += valid;
      }
    }
  }

  // ---- per-wave reduction -> one float2 per WAVE (no 2nd barrier) ----
#pragma unroll
  for (int off = 32; off > 0; off >>= 1) {
    lsum += __shfl_down(lsum, off, 64);
    lcnt += __shfl_down(lcnt, off, 64);
  }
  if (lane == 0) {
    const int bid = (blockIdx.z * GY + blockIdx.y) * GX + blockIdx.x;
    partials[bid * 4 + wv] = make_float2(lsum, (float)lcnt);
  }
}

extern "C" __global__ __launch_bounds__(1024)
void boundary_loss_final(const float2* __restrict__ partials,
                         float* __restrict__ out)
{
  __shared__ double red_s[16];
  __shared__ double red_c[16];
  const int tid = threadIdx.x;
  double s = 0.0, cc = 0.0;
  for (int i = tid; i < NPART; i += 1024) {
    const float2 p = partials[i];
    s += (double)p.x;
    cc += (double)p.y;
  }
#pragma unroll
  for (int off = 32; off > 0; off >>= 1) {
    s += __shfl_down(s, off, 64);
    cc += __shfl_down(cc, off, 64);
  }
  const int wave = tid >> 6;
  if ((tid & 63) == 0) { red_s[wave] = s; red_c[wave] = cc; }
  __syncthreads();
  if (tid == 0) {
    double ts = 0.0, tc = 0.0;
#pragma unroll
    for (int i = 0; i < 16; ++i) { ts += red_s[i]; tc += red_c[i]; }
    if (tc < 1.0) tc = 1.0;
    out[0] = (float)(-ts / tc);
  }
}

extern "C" void kernel_launch(void* const* d_in, const int* in_sizes, int n_in,
                              void* d_out, int out_size, void* d_ws, size_t ws_size,
                              hipStream_t stream)
{
  const float* logits = (const float*)d_in[0];
  const int* labels = (const int*)d_in[1];
  float* out = (float*)d_out;
  float2* partials = (float2*)d_ws;  // NPART*8 B = 215,040 B; every slot
                                     // written by main -> no init needed.

  dim3 grid(GX, GY, B_);
  boundary_loss_main<<<grid, 256, 0, stream>>>(logits, labels, partials);
  boundary_loss_final<<<1, 1024, 0, stream>>>(partials, out);
}